// Round 5
// baseline (547.615 us; speedup 1.0000x reference)
//
#include <hip/hip_runtime.h>
#include <math.h>

#define B_   16
#define D_   256
#define T_   4096
#define NQn  8
#define K_   1024
#define DC_  128
#define M_   65536

typedef short bf16x8 __attribute__((ext_vector_type(8)));
typedef float f32x4  __attribute__((ext_vector_type(4)));

static __device__ __forceinline__ unsigned short f2bf(float f) {
    unsigned u = __float_as_uint(f);
    unsigned r = (u + 0x7fffu + ((u >> 16) & 1u)) >> 16;
    return (unsigned short)r;
}
static __device__ __forceinline__ float bf2f(unsigned short h) {
    return __uint_as_float(((unsigned)h) << 16);
}

__global__ void zero_acc_k(float* acc) { acc[0] = 0.f; }
__global__ void final_k(const float* __restrict__ acc, float* __restrict__ out) {
    out[0] = acc[0] * (1.f / 262144.f);   // / (4 * B * T)
}

// ---------------------------------------------------------------- precompute
// F[k][d] = (embed[k]·Win[:,d]) / 64   (bf16, natural row-major)
// g[k]    = (|e_k|^2 - 2 b_in·e_k)/128
// table[k][d] = embed[k]·Wout[d] + b_out[d]   (bf16)
__global__ __launch_bounds__(256) void prep_k(
    const float* __restrict__ Win,   // (8,128,256)
    const float* __restrict__ bin,   // (8,128)
    const float* __restrict__ Wout,  // (8,256,128)
    const float* __restrict__ bout,  // (8,256)
    const float* __restrict__ emb,   // (8,1024,128)
    unsigned short* __restrict__ Fz, // (4,1024,256) bf16
    unsigned short* __restrict__ tab,// (3,1024,256) bf16
    float* __restrict__ g)           // (4,1024)
{
    __shared__ float E[16][128];
    __shared__ float sb[128];
    const int iq = blockIdx.x >> 6;
    const int k0 = (blockIdx.x & 63) << 4;
    const int tid = threadIdx.x;
    {
        const float* src = emb + ((size_t)iq * K_ + k0) * DC_;
        #pragma unroll
        for (int it = 0; it < 2; ++it) {
            int lin = it * 1024 + tid * 4;
            float4 v = *(const float4*)(src + lin);
            *(float4*)&E[lin >> 7][lin & 127] = v;
        }
        if (tid < 32) *(float4*)&sb[tid * 4] = *(const float4*)(bin + iq * DC_ + tid * 4);
    }
    __syncthreads();
    if (tid < 16) {
        float e2 = 0.f, be = 0.f;
        for (int c2 = 0; c2 < 128; ++c2) {
            float e = E[tid][c2];
            e2 += e * e; be += sb[c2] * e;
        }
        g[iq * K_ + k0 + tid] = (e2 - 2.f * be) * (1.f / 128.f);
    }
    {
        const int d = tid;
        float acc[16];
        #pragma unroll
        for (int kk = 0; kk < 16; ++kk) acc[kk] = 0.f;
        const float* wp = Win + (size_t)iq * DC_ * D_ + d;
        for (int c2 = 0; c2 < 128; ++c2) {
            float w = wp[(size_t)c2 * D_];
            #pragma unroll
            for (int kk = 0; kk < 16; ++kk) acc[kk] = fmaf(E[kk][c2], w, acc[kk]);
        }
        unsigned short* Fq = Fz + ((size_t)iq << 18);
        #pragma unroll
        for (int kk = 0; kk < 16; ++kk)
            Fq[((size_t)(k0 + kk) << 8) + d] = f2bf(acc[kk] * 0.015625f);
    }
    if (iq < 3) {
        const int d = tid;
        float acc[16];
        #pragma unroll
        for (int kk = 0; kk < 16; ++kk) acc[kk] = 0.f;
        const float* wp = Wout + ((size_t)iq * D_ + d) * DC_;
        for (int c2 = 0; c2 < 128; ++c2) {
            float w = wp[c2];
            #pragma unroll
            for (int kk = 0; kk < 16; ++kk) acc[kk] = fmaf(E[kk][c2], w, acc[kk]);
        }
        float bo = bout[iq * D_ + d];
        unsigned short* tq = tab + ((size_t)iq << 18);
        #pragma unroll
        for (int kk = 0; kk < 16; ++kk)
            tq[((size_t)(k0 + kk) << 8) + d] = f2bf(acc[kk] + bo);
    }
}

// ---------------------------------------------------------------- fused 4-quantizer RVQ, L2-direct
// 256 blocks x 512 threads (8 waves = 2/SIMD). Wave owns 32 rows (rf=2 x 16),
// residual in VGPRs (loaded straight from X, transposed+converted in-register).
// A-fragments (F codes) stream from L2 with a depth-2, 3-buffer register
// pipeline. No LDS data path, no barriers in the hot loop.

#define EPI(ACC, RF, CBB, GV) do { \
    float l0 = (ACC)[0] - (GV).x, l1 = (ACC)[1] - (GV).y; \
    float l2 = (ACC)[2] - (GV).z, l3 = (ACC)[3] - (GV).w; \
    lsum[RF] += (__expf(l0) + __expf(l1)) + (__expf(l2) + __expf(l3)); \
    float m01 = fmaxf(l0, l1), m23 = fmaxf(l2, l3); \
    float lm = fmaxf(m01, m23); \
    int jl = (m23 > m01) ? ((l3 > l2) ? 3 : 2) : ((l1 > l0) ? 1 : 0); \
    if (lm > bv[RF]) { bv[RF] = lm; bi[RF] = (CBB) + jl; } \
    if ((tgt[RF] >> 2) == ((CBB) >> 2)) { \
        int myj = tgt[RF] & 3; \
        float pj = (myj & 2) ? ((myj & 1) ? l3 : l2) : ((myj & 1) ? l1 : l0); \
        pick[RF] = pj; \
    } \
} while (0)

#define STEP(AF, CF) do { \
    const int cbb = ((CF) << 4) + (lg4 << 2); \
    float4 gv = *(const float4*)&gq[cbb]; \
    f32x4 ac0 = {0.f, 0.f, 0.f, 0.f}; \
    f32x4 ac1 = ac0; \
    _Pragma("unroll") \
    for (int s = 0; s < 8; ++s) { \
        ac0 = __builtin_amdgcn_mfma_f32_16x16x32_bf16(AF[s], xb[0][s], ac0, 0, 0, 0); \
        ac1 = __builtin_amdgcn_mfma_f32_16x16x32_bf16(AF[s], xb[1][s], ac1, 0, 0, 0); \
    } \
    EPI(ac0, 0, cbb, gv); \
    EPI(ac1, 1, cbb, gv); \
} while (0)

#define LOADF(BUF, CF) do { \
    const unsigned short* fp = Fq + (size_t)(((CF) << 4) + l15) * 256 + (lg4 << 3); \
    _Pragma("unroll") \
    for (int s = 0; s < 8; ++s) BUF[s] = *(const bf16x8*)(fp + (s << 5)); \
} while (0)

__global__ __launch_bounds__(512, 2) void rvq_k(
    const float* __restrict__ X,             // (B,256,4096) f32
    const unsigned short* __restrict__ F,    // (4,1024,256) bf16, scaled 1/64
    const unsigned short* __restrict__ tab,  // (3,1024,256) bf16
    const float* __restrict__ g,             // (4,1024)
    const int* __restrict__ tlc,             // (B,NQ,T)
    float* __restrict__ accp)
{
    // occupancy shim: 96 KB LDS -> exactly 1 block (8 waves = 2/SIMD) per CU,
    // so the 256 blocks spread one-per-CU.
    __shared__ __align__(16) char shim[98304];
    *(volatile char*)&shim[threadIdx.x] = 0;

    const int tid  = threadIdx.x;
    const int lane = tid & 63;
    const int wv   = tid >> 6;
    const int l15  = lane & 15;
    const int lg4  = lane >> 4;
    const int row_base = blockIdx.x * 256 + wv * 32;

    // residual fragments: 32 rows x 256 d, bf16, 64 VGPRs.
    // Loaded directly from X (B,D,T): per rf all 32 rows share one b.
    bf16x8 xb[2][8];
    #pragma unroll
    for (int rf = 0; rf < 2; ++rf) {
        const int row = row_base + rf * 16 + l15;
        const float* xpr = X + ((size_t)(row >> 12) << 20) + (row & (T_ - 1));
        #pragma unroll
        for (int s = 0; s < 8; ++s) {
            bf16x8 v;
            #pragma unroll
            for (int j = 0; j < 8; ++j) {
                float f = xpr[(size_t)((s << 5) + (lg4 << 3) + j) << 12];
                v[j] = (short)f2bf(f);
            }
            xb[rf][s] = v;
        }
    }

    float loss = 0.f;

    #pragma unroll 1
    for (int q = 0; q < 4; ++q) {
        const unsigned short* Fq = F + ((size_t)q << 18);
        const float* gq = g + (q << 10);

        int tgt[2];
        #pragma unroll
        for (int rf = 0; rf < 2; ++rf) {
            int row = row_base + rf * 16 + l15;
            tgt[rf] = tlc[(size_t)(row >> 12) * (NQn * T_) + q * T_ + (row & (T_ - 1))];
        }

        float lsum[2] = {0.f, 0.f};
        float bv[2]   = {-1e30f, -1e30f};
        int   bi[2]   = {0, 0};
        float pick[2] = {0.f, 0.f};

        bf16x8 a0[8], a1[8], a2[8];
        LOADF(a0, 0);
        LOADF(a1, 1);

        #pragma unroll 1
        for (int t3 = 0; t3 < 21; ++t3) {
            const int base = t3 * 3;
            LOADF(a2, base + 2);
            STEP(a0, base);
            LOADF(a0, base + 3);            // base+3 <= 63 always
            STEP(a1, base + 1);
            if (t3 < 20) LOADF(a1, base + 4);
            STEP(a2, base + 2);
        }
        STEP(a0, 63);

        // combine the 4 lg4-groups (each holds 256 of the 1024 codes per row)
        #pragma unroll
        for (int rf = 0; rf < 2; ++rf) {
            #pragma unroll
            for (int off = 16; off <= 32; off <<= 1) {
                lsum[rf] += __shfl_xor(lsum[rf], off);
                pick[rf] += __shfl_xor(pick[rf], off);
                float om = __shfl_xor(bv[rf], off);
                int   ob = __shfl_xor(bi[rf], off);
                if (om > bv[rf] || (om == bv[rf] && ob < bi[rf])) { bv[rf] = om; bi[rf] = ob; }
            }
            if (lane < 16) loss += __logf(lsum[rf]) - pick[rf];
        }

        // residual -= table[argmax]  (in-register, bf16)
        if (q < 3) {
            const unsigned short* tq = tab + ((size_t)q << 18);
            #pragma unroll
            for (int rf = 0; rf < 2; ++rf) {
                const unsigned short* trow = tq + ((size_t)bi[rf] << 8) + (lg4 << 3);
                #pragma unroll
                for (int s = 0; s < 8; ++s) {
                    bf16x8 tv = *(const bf16x8*)(trow + (s << 5));
                    bf16x8 xv = xb[rf][s];
                    #pragma unroll
                    for (int j = 0; j < 8; ++j)
                        xv[j] = (short)f2bf(bf2f((unsigned short)xv[j]) - bf2f((unsigned short)tv[j]));
                    xb[rf][s] = xv;
                }
            }
            __syncthreads();   // keep waves loosely in phase for L1 locality on F
        }
    }

    #pragma unroll
    for (int off = 1; off < 64; off <<= 1) loss += __shfl_xor(loss, off);
    if (lane == 0) atomicAdd(accp, loss);
}

// ---------------------------------------------------------------- launch
extern "C" void kernel_launch(void* const* d_in, const int* in_sizes, int n_in,
                              void* d_out, int out_size, void* d_ws, size_t ws_size,
                              hipStream_t stream)
{
    (void)in_sizes; (void)n_in; (void)out_size; (void)ws_size;
    const float* dstart = (const float*)d_in[0];
    const int*   tlc    = (const int*)d_in[1];
    const float* Win    = (const float*)d_in[2];
    const float* bin    = (const float*)d_in[3];
    const float* Wout   = (const float*)d_in[4];
    const float* bout   = (const float*)d_in[5];
    const float* emb    = (const float*)d_in[6];

    char* ws = (char*)d_ws;
    size_t off = 0;
    unsigned short* Fz  = (unsigned short*)(ws + off); off += (size_t)4 * K_ * D_ * 2;    // 2 MB
    unsigned short* tab = (unsigned short*)(ws + off); off += (size_t)3 * K_ * D_ * 2;    // 1.5 MB
    float*          g   = (float*)(ws + off);          off += (size_t)4 * K_ * 4;
    float*          accp= (float*)(ws + off);          off += 256;

    zero_acc_k<<<1, 1, 0, stream>>>(accp);
    prep_k<<<256, 256, 0, stream>>>(Win, bin, Wout, bout, emb, Fz, tab, g);
    rvq_k<<<256, 512, 0, stream>>>(dstart, Fz, tab, g, tlc, accp);
    final_k<<<1, 1, 0, stream>>>(accp, (float*)d_out);
}

// Round 6
// 195.197 us; speedup vs baseline: 2.8054x; 2.8054x over previous
//
#include <hip/hip_runtime.h>
#include <math.h>

#define B_   16
#define D_   256
#define T_   4096
#define NQn  8
#define K_   1024
#define DC_  128
#define M_   65536

typedef short bf16x8 __attribute__((ext_vector_type(8)));
typedef float f32x4  __attribute__((ext_vector_type(4)));

static __device__ __forceinline__ unsigned short f2bf(float f) {
    unsigned u = __float_as_uint(f);
    unsigned r = (u + 0x7fffu + ((u >> 16) & 1u)) >> 16;
    return (unsigned short)r;
}
static __device__ __forceinline__ float bf2f(unsigned short h) {
    return __uint_as_float(((unsigned)h) << 16);
}

__global__ void zero_acc_k(float* acc) { acc[0] = 0.f; }
__global__ void final_k(const float* __restrict__ acc, float* __restrict__ out) {
    out[0] = acc[0] * (1.f / 262144.f);   // / (4 * B * T)
}

// ---------------------------------------------------------------- stream reformat
// stream per q (320KB): [Win_perm 4 chunks][emb_perm 16 chunks], chunk = 16KB,
// laid out in EXACT wave read-order: unit16(u) = ((blk)*64 + lane)*16B.
//  Win chunk S: blk = t_l*8+s', content Win[q][c=32S+16t_l+l15][d=32s'+8lg4+j]
//  emb chunk ch: blk = cf_l*4+s, content emb[q][code=(ch*4+cf_l)*16+l15][psi]/64
//    psi = 32s + 16*(j>>2) + 4*lg4 + (j&3)
// block 320: copies b_in (first 4 q) into gbias[4096..4607]
__global__ __launch_bounds__(256) void reformat_k(
    const float* __restrict__ Win, const float* __restrict__ bin,
    const float* __restrict__ emb, unsigned short* __restrict__ stream,
    float* __restrict__ gbias)
{
    const int bid = blockIdx.x;
    const int tid = threadIdx.x;
    if (bid == 320) {
        gbias[4096 + tid]       = bin[tid];
        gbias[4096 + 256 + tid] = bin[256 + tid];
        return;
    }
    int u = bid * 256 + tid;              // 16B unit, 0..81919
    int idx = u >> 10;                    // chunk 0..79
    int q = idx / 20, r = idx - q * 20;
    int w = u & 1023;
    int lane = w & 63, blk = w >> 6;
    int l15 = lane & 15, lg4 = lane >> 4;
    unsigned short o[8];
    if (r < 4) {
        int c  = 32 * r + 16 * (blk >> 3) + l15;
        int d0 = 32 * (blk & 7) + 8 * lg4;
        const float* s = Win + ((size_t)q * DC_ + c) * D_ + d0;
        #pragma unroll
        for (int j = 0; j < 8; ++j) o[j] = f2bf(s[j]);
    } else {
        int ch = r - 4;
        int code = (ch * 4 + (blk >> 2)) * 16 + l15;
        int s4 = blk & 3;
        const float* s = emb + ((size_t)q * K_ + code) * DC_ + 32 * s4 + 4 * lg4;
        #pragma unroll
        for (int j = 0; j < 8; ++j)
            o[j] = f2bf(s[16 * (j >> 2) + (j & 3)] * 0.015625f);
    }
    *(int4*)&stream[(size_t)u * 8] = *(int4*)o;
}

// ---------------------------------------------------------------- tab + g
// g[k] = |e_k|^2 / 128 ; tab[k][d] = embed[k]·Wout[d] + b_out[d]
__global__ __launch_bounds__(256) void prep_tab_k(
    const float* __restrict__ Wout, const float* __restrict__ bout,
    const float* __restrict__ emb,
    unsigned short* __restrict__ tab, float* __restrict__ gbias)
{
    __shared__ float E[16][128];
    const int iq = blockIdx.x >> 6;
    const int k0 = (blockIdx.x & 63) << 4;
    const int tid = threadIdx.x;
    {
        const float* src = emb + ((size_t)iq * K_ + k0) * DC_;
        #pragma unroll
        for (int it = 0; it < 2; ++it) {
            int lin = it * 1024 + tid * 4;
            float4 v = *(const float4*)(src + lin);
            *(float4*)&E[lin >> 7][lin & 127] = v;
        }
    }
    __syncthreads();
    if (tid < 16) {
        float e2 = 0.f;
        for (int c2 = 0; c2 < 128; ++c2) { float e = E[tid][c2]; e2 += e * e; }
        gbias[iq * K_ + k0 + tid] = e2 * (1.f / 128.f);
    }
    if (iq < 3) {
        const int d = tid;
        float acc[16];
        #pragma unroll
        for (int kk = 0; kk < 16; ++kk) acc[kk] = 0.f;
        const float* wp = Wout + ((size_t)iq * D_ + d) * DC_;
        for (int c2 = 0; c2 < 128; ++c2) {
            float w = wp[c2];
            #pragma unroll
            for (int kk = 0; kk < 16; ++kk) acc[kk] = fmaf(E[kk][c2], w, acc[kk]);
        }
        float bo = bout[iq * D_ + d];
        unsigned short* tq = tab + ((size_t)iq << 18);
        #pragma unroll
        for (int kk = 0; kk < 16; ++kk)
            tq[((size_t)(k0 + kk) << 8) + d] = f2bf(acc[kk] + bo);
    }
}

// ---------------------------------------------------------------- fused RVQ
#define EPI(ACC, RF, CBB, GV) do { \
    float l0 = (ACC)[0] - (GV).x, l1 = (ACC)[1] - (GV).y; \
    float l2 = (ACC)[2] - (GV).z, l3 = (ACC)[3] - (GV).w; \
    lsum[RF] += (__expf(l0) + __expf(l1)) + (__expf(l2) + __expf(l3)); \
    float m01 = fmaxf(l0, l1), m23 = fmaxf(l2, l3); \
    float lm = fmaxf(m01, m23); \
    int jl = (m23 > m01) ? ((l3 > l2) ? 3 : 2) : ((l1 > l0) ? 1 : 0); \
    if (lm > bv[RF]) { bv[RF] = lm; bi[RF] = (CBB) + jl; } \
    if ((tgt[RF] >> 2) == ((CBB) >> 2)) { \
        int myj = tgt[RF] & 3; \
        float pj = (myj & 2) ? ((myj & 1) ? l3 : l2) : ((myj & 1) ? l1 : l0); \
        pick[RF] = pj; \
    } \
} while (0)

#define GLDS(SRC, DSTOFF) __builtin_amdgcn_global_load_lds( \
    (const __attribute__((address_space(1))) unsigned int*)(SRC), \
    (__attribute__((address_space(3))) unsigned int*)(LDSM + (DSTOFF)), 16, 0, 0)

#define STAGE(CI) do { \
    int nx_ = (CI); if (nx_ >= 80) nx_ -= 80; \
    const char* s_ = (const char*)stream + ((size_t)nx_ << 14) + wv * 1024 + (lane << 4); \
    int db_ = (nx_ & 3) << 14; \
    GLDS(s_, db_ + wv * 1024); \
    GLDS(s_ + 8192, db_ + 8192 + wv * 1024); \
} while (0)

// vmcnt(own chunk done) -> barrier (everyone's done, prev reads done) -> stage i+3
#define ITERTOP(CI) do { \
    asm volatile("s_waitcnt vmcnt(4)" ::: "memory"); \
    __builtin_amdgcn_s_barrier(); \
    STAGE((CI) + 3); \
    __builtin_amdgcn_sched_barrier(0); \
} while (0)

__global__ __launch_bounds__(512, 2) void rvq_k(
    const float* __restrict__ X,              // (B,256,4096) f32
    const unsigned short* __restrict__ stream,
    const float* __restrict__ gbias,          // [g 4096][bias 512] f32
    const unsigned short* __restrict__ tab,   // (3,1024,256) bf16
    const int* __restrict__ tlc,
    float* __restrict__ accp)
{
    __shared__ __align__(16) char LDSM[84992]; // 64KB ring + 18KB g/bias + pad
    float* gb = (float*)(LDSM + 65536);

    const int tid  = threadIdx.x;
    const int lane = tid & 63;
    const int wv   = tid >> 6;
    const int l15  = lane & 15;
    const int lg4  = lane >> 4;
    const int row_base = blockIdx.x * 256 + wv * 32;

    // residual fragments: 32 rows x 256 d, bf16 in regs (natural d-slot order)
    bf16x8 xb[2][8];
    #pragma unroll
    for (int rf = 0; rf < 2; ++rf) {
        const int row = row_base + rf * 16 + l15;
        const float* xpr = X + ((size_t)(row >> 12) << 20) + (row & (T_ - 1));
        #pragma unroll
        for (int s = 0; s < 8; ++s) {
            bf16x8 v;
            #pragma unroll
            for (int j = 0; j < 8; ++j) {
                float f = xpr[(size_t)((s << 5) + (lg4 << 3) + j) << 12];
                v[j] = (short)f2bf(f);
            }
            xb[rf][s] = v;
        }
    }
    __builtin_amdgcn_sched_barrier(0);   // all X loads consumed before staging begins

    // prologue staging: g/bias (1152 units) + chunks 0..2
    {
        const char* gs = (const char*)gbias;
        GLDS(gs + tid * 16,        65536 + wv * 1024);
        GLDS(gs + 8192 + tid * 16, 65536 + 8192 + wv * 1024);
        if (tid < 128) GLDS(gs + 16384 + tid * 16, 65536 + 16384 + wv * 1024);
    }
    STAGE(0); STAGE(1); STAGE(2);

    float loss = 0.f;
    int ci = 0;

    #pragma unroll 1
    for (int q = 0; q < 4; ++q) {
        int tgt[2];
        #pragma unroll
        for (int rf = 0; rf < 2; ++rf) {
            int row = row_base + rf * 16 + l15;
            tgt[rf] = tlc[(size_t)(row >> 12) * (NQn * T_) + q * T_ + (row & (T_ - 1))];
        }

        // ---- GEMM1: xp = x·Win^T + b_in  (4 chunks -> xpf[rf][S]) ----
        bf16x8 xpf[2][4];
        #pragma unroll
        for (int S = 0; S < 4; ++S) {
            ITERTOP(ci);
            const int bufo = (ci & 3) << 14;
            f32x4 a00 = {0.f,0.f,0.f,0.f}, a01 = a00, a10 = a00, a11 = a00;
            #pragma unroll
            for (int sp = 0; sp < 8; ++sp) {
                bf16x8 w0 = *(const bf16x8*)(LDSM + bufo + ((sp) * 64 + lane) * 16);
                bf16x8 w1 = *(const bf16x8*)(LDSM + bufo + ((8 + sp) * 64 + lane) * 16);
                a00 = __builtin_amdgcn_mfma_f32_16x16x32_bf16(w0, xb[0][sp], a00, 0, 0, 0);
                a01 = __builtin_amdgcn_mfma_f32_16x16x32_bf16(w0, xb[1][sp], a01, 0, 0, 0);
                a10 = __builtin_amdgcn_mfma_f32_16x16x32_bf16(w1, xb[0][sp], a10, 0, 0, 0);
                a11 = __builtin_amdgcn_mfma_f32_16x16x32_bf16(w1, xb[1][sp], a11, 0, 0, 0);
            }
            float4 b0 = *(const float4*)(gb + 4096 + q * 128 + 32 * S + 4 * lg4);
            float4 b1 = *(const float4*)(gb + 4096 + q * 128 + 32 * S + 16 + 4 * lg4);
            {
                bf16x8 v;
                v[0] = (short)f2bf(a00[0] + b0.x); v[1] = (short)f2bf(a00[1] + b0.y);
                v[2] = (short)f2bf(a00[2] + b0.z); v[3] = (short)f2bf(a00[3] + b0.w);
                v[4] = (short)f2bf(a10[0] + b1.x); v[5] = (short)f2bf(a10[1] + b1.y);
                v[6] = (short)f2bf(a10[2] + b1.z); v[7] = (short)f2bf(a10[3] + b1.w);
                xpf[0][S] = v;
            }
            {
                bf16x8 v;
                v[0] = (short)f2bf(a01[0] + b0.x); v[1] = (short)f2bf(a01[1] + b0.y);
                v[2] = (short)f2bf(a01[2] + b0.z); v[3] = (short)f2bf(a01[3] + b0.w);
                v[4] = (short)f2bf(a11[0] + b1.x); v[5] = (short)f2bf(a11[1] + b1.y);
                v[6] = (short)f2bf(a11[2] + b1.z); v[7] = (short)f2bf(a11[3] + b1.w);
                xpf[1][S] = v;
            }
            ++ci;
        }

        // ---- GEMM2: logits vs all 1024 codes (16 chunks) ----
        float lsum[2] = {0.f, 0.f};
        float bv[2]   = {-1e30f, -1e30f};
        int   bi[2]   = {0, 0};
        float pick[2] = {0.f, 0.f};

        #pragma unroll 1
        for (int ch = 0; ch < 16; ++ch) {
            ITERTOP(ci);
            const int bufo = (ci & 3) << 14;
            #pragma unroll
            for (int cfp = 0; cfp < 2; ++cfp) {
                bf16x8 a[2][4];
                #pragma unroll
                for (int cl = 0; cl < 2; ++cl)
                    #pragma unroll
                    for (int s = 0; s < 4; ++s)
                        a[cl][s] = *(const bf16x8*)(LDSM + bufo +
                                     (((cfp * 2 + cl) * 4 + s) * 64 + lane) * 16);
                f32x4 c00 = {0.f,0.f,0.f,0.f}, c01 = c00, c10 = c00, c11 = c00;
                #pragma unroll
                for (int s = 0; s < 4; ++s) {
                    c00 = __builtin_amdgcn_mfma_f32_16x16x32_bf16(a[0][s], xpf[0][s], c00, 0, 0, 0);
                    c01 = __builtin_amdgcn_mfma_f32_16x16x32_bf16(a[0][s], xpf[1][s], c01, 0, 0, 0);
                    c10 = __builtin_amdgcn_mfma_f32_16x16x32_bf16(a[1][s], xpf[0][s], c10, 0, 0, 0);
                    c11 = __builtin_amdgcn_mfma_f32_16x16x32_bf16(a[1][s], xpf[1][s], c11, 0, 0, 0);
                }
                {
                    const int cfg = ch * 4 + cfp * 2;
                    float4 gv = *(const float4*)(gb + q * 1024 + cfg * 16 + lg4 * 4);
                    const int cbb = cfg * 16 + lg4 * 4;
                    EPI(c00, 0, cbb, gv);
                    EPI(c01, 1, cbb, gv);
                }
                {
                    const int cfg = ch * 4 + cfp * 2 + 1;
                    float4 gv = *(const float4*)(gb + q * 1024 + cfg * 16 + lg4 * 4);
                    const int cbb = cfg * 16 + lg4 * 4;
                    EPI(c10, 0, cbb, gv);
                    EPI(c11, 1, cbb, gv);
                }
            }
            ++ci;
        }

        // ---- combine lane-groups, loss, residual update ----
        #pragma unroll
        for (int rf = 0; rf < 2; ++rf) {
            #pragma unroll
            for (int off = 16; off <= 32; off <<= 1) {
                lsum[rf] += __shfl_xor(lsum[rf], off);
                pick[rf] += __shfl_xor(pick[rf], off);
                float om = __shfl_xor(bv[rf], off);
                int   ob = __shfl_xor(bi[rf], off);
                if (om > bv[rf] || (om == bv[rf] && ob < bi[rf])) { bv[rf] = om; bi[rf] = ob; }
            }
            if (lane < 16) loss += __logf(lsum[rf]) - pick[rf];
        }
        if (q < 3) {
            const unsigned short* tq = tab + ((size_t)q << 18);
            #pragma unroll
            for (int rf = 0; rf < 2; ++rf) {
                const unsigned short* trow = tq + ((size_t)bi[rf] << 8) + (lg4 << 3);
                #pragma unroll
                for (int s = 0; s < 8; ++s) {
                    bf16x8 tv = *(const bf16x8*)(trow + (s << 5));
                    bf16x8 xv = xb[rf][s];
                    #pragma unroll
                    for (int j = 0; j < 8; ++j)
                        xv[j] = (short)f2bf(bf2f((unsigned short)xv[j]) - bf2f((unsigned short)tv[j]));
                    xb[rf][s] = xv;
                }
            }
        }
    }

    asm volatile("s_waitcnt vmcnt(0)" ::: "memory");  // drain dummy tail stages
    #pragma unroll
    for (int off = 1; off < 64; off <<= 1) loss += __shfl_xor(loss, off);
    if (lane == 0) atomicAdd(accp, loss);
}

// ---------------------------------------------------------------- launch
extern "C" void kernel_launch(void* const* d_in, const int* in_sizes, int n_in,
                              void* d_out, int out_size, void* d_ws, size_t ws_size,
                              hipStream_t stream_)
{
    (void)in_sizes; (void)n_in; (void)out_size; (void)ws_size;
    const float* dstart = (const float*)d_in[0];
    const int*   tlc    = (const int*)d_in[1];
    const float* Win    = (const float*)d_in[2];
    const float* bin    = (const float*)d_in[3];
    const float* Wout   = (const float*)d_in[4];
    const float* bout   = (const float*)d_in[5];
    const float* emb    = (const float*)d_in[6];

    char* ws = (char*)d_ws;
    size_t off = 0;
    unsigned short* strm = (unsigned short*)(ws + off); off += (size_t)80 * 16384;       // 1.25 MB
    unsigned short* tab  = (unsigned short*)(ws + off); off += (size_t)3 * K_ * D_ * 2;  // 1.5 MB
    float*          gbias= (float*)(ws + off);          off += (size_t)4608 * 4;         // 18 KB
    float*          accp = (float*)(ws + off);          off += 256;

    zero_acc_k<<<1, 1, 0, stream_>>>(accp);
    reformat_k<<<321, 256, 0, stream_>>>(Win, bin, emb, strm, gbias);
    prep_tab_k<<<256, 256, 0, stream_>>>(Wout, bout, emb, tab, gbias);
    rvq_k<<<256, 512, 0, stream_>>>(dstart, strm, gbias, tab, tlc, accp);
    final_k<<<1, 1, 0, stream_>>>(accp, (float*)d_out);
}

// Round 8
// 168.824 us; speedup vs baseline: 3.2437x; 1.1562x over previous
//
#include <hip/hip_runtime.h>
#include <math.h>

#define B_   16
#define D_   256
#define T_   4096
#define NQn  8
#define K_   1024
#define DC_  128
#define M_   65536

typedef short bf16x8 __attribute__((ext_vector_type(8)));
typedef float f32x4  __attribute__((ext_vector_type(4)));

static __device__ __forceinline__ unsigned short f2bf(float f) {
    unsigned u = __float_as_uint(f);
    unsigned r = (u + 0x7fffu + ((u >> 16) & 1u)) >> 16;
    return (unsigned short)r;
}

// packed f32x2 -> bf16x2 (RNE), 1 instruction
static __device__ __forceinline__ int pk2(float lo, float hi) {
    int r;
    asm("v_cvt_pk_bf16_f32 %0, %1, %2" : "=v"(r) : "v"(lo), "v"(hi));
    return r;
}
// (x - t) elementwise on packed bf16x2
static __device__ __forceinline__ int sub2(int x, int t) {
    float xl = __uint_as_float(((unsigned)x) << 16);
    float xh = __uint_as_float(((unsigned)x) & 0xFFFF0000u);
    float tl = __uint_as_float(((unsigned)t) << 16);
    float th = __uint_as_float(((unsigned)t) & 0xFFFF0000u);
    return pk2(xl - tl, xh - th);
}

static __device__ __forceinline__ f32x4 MFMA(bf16x8 a, bf16x8 b, f32x4 c) {
    return __builtin_amdgcn_mfma_f32_16x16x32_bf16(a, b, c, 0, 0, 0);
}

#define EXP2(x) __builtin_amdgcn_exp2f(x)
#define LOG2(x) __builtin_amdgcn_logf(x)

__global__ void zero_acc_k(float* acc) { acc[0] = 0.f; }
__global__ void final_k(const float* __restrict__ acc, float* __restrict__ out) {
    out[0] = acc[0] * (1.f / 262144.f);   // / (4 * B * T)
}

// ---------------------------------------------------------------- stream reformat
// Same layout as R6; emb now scaled by 1/(64*ln2) for exp2-domain logits.
__global__ __launch_bounds__(256) void reformat_k(
    const float* __restrict__ Win, const float* __restrict__ bin,
    const float* __restrict__ emb, unsigned short* __restrict__ stream,
    float* __restrict__ gbias)
{
    const int bid = blockIdx.x;
    const int tid = threadIdx.x;
    if (bid == 320) {
        gbias[4096 + tid]       = bin[tid];
        gbias[4096 + 256 + tid] = bin[256 + tid];
        return;
    }
    int u = bid * 256 + tid;              // 16B unit, 0..81919
    int idx = u >> 10;                    // chunk 0..79
    int q = idx / 20, r = idx - q * 20;
    int w = u & 1023;
    int lane = w & 63, blk = w >> 6;
    int l15 = lane & 15, lg4 = lane >> 4;
    unsigned short o[8];
    if (r < 4) {
        int c  = 32 * r + 16 * (blk >> 3) + l15;
        int d0 = 32 * (blk & 7) + 8 * lg4;
        const float* s = Win + ((size_t)q * DC_ + c) * D_ + d0;
        #pragma unroll
        for (int j = 0; j < 8; ++j) o[j] = f2bf(s[j]);
    } else {
        int ch = r - 4;
        int code = (ch * 4 + (blk >> 2)) * 16 + l15;
        int s4 = blk & 3;
        const float* s = emb + ((size_t)q * K_ + code) * DC_ + 32 * s4 + 4 * lg4;
        const float ESC = 1.44269504089f / 64.0f;
        #pragma unroll
        for (int j = 0; j < 8; ++j)
            o[j] = f2bf(s[16 * (j >> 2) + (j & 3)] * ESC);
    }
    *(int4*)&stream[(size_t)u * 8] = *(int4*)o;
}

// ---------------------------------------------------------------- tab + g
// g[k] = |e_k|^2/(128*ln2) ; tab[k][d] = embed[k]·Wout[d] + b_out[d]
__global__ __launch_bounds__(256) void prep_tab_k(
    const float* __restrict__ Wout, const float* __restrict__ bout,
    const float* __restrict__ emb,
    unsigned short* __restrict__ tab, float* __restrict__ gbias)
{
    __shared__ float E[16][128];
    const int iq = blockIdx.x >> 6;
    const int k0 = (blockIdx.x & 63) << 4;
    const int tid = threadIdx.x;
    {
        const float* src = emb + ((size_t)iq * K_ + k0) * DC_;
        #pragma unroll
        for (int it = 0; it < 2; ++it) {
            int lin = it * 1024 + tid * 4;
            float4 v = *(const float4*)(src + lin);
            *(float4*)&E[lin >> 7][lin & 127] = v;
        }
    }
    __syncthreads();
    if (tid < 16) {
        float e2 = 0.f;
        for (int c2 = 0; c2 < 128; ++c2) { float e = E[tid][c2]; e2 += e * e; }
        gbias[iq * K_ + k0 + tid] = e2 * (1.44269504089f / 128.f);
    }
    if (iq < 3) {
        const int d = tid;
        float acc[16];
        #pragma unroll
        for (int kk = 0; kk < 16; ++kk) acc[kk] = 0.f;
        const float* wp = Wout + ((size_t)iq * D_ + d) * DC_;
        for (int c2 = 0; c2 < 128; ++c2) {
            float w = wp[c2];
            #pragma unroll
            for (int kk = 0; kk < 16; ++kk) acc[kk] = fmaf(E[kk][c2], w, acc[kk]);
        }
        float bo = bout[iq * D_ + d];
        unsigned short* tq = tab + ((size_t)iq << 18);
        #pragma unroll
        for (int kk = 0; kk < 16; ++kk)
            tq[((size_t)(k0 + kk) << 8) + d] = f2bf(acc[kk] + bo);
    }
}

// ---------------------------------------------------------------- fused RVQ
#define GLDS(SRC, DST) __builtin_amdgcn_global_load_lds( \
    (const __attribute__((address_space(1))) unsigned int*)(SRC), \
    (__attribute__((address_space(3))) unsigned int*)(DST), 16, 0, 0)

// ring: 3 x 16KB slots at LDSM+0..48K. gb at 49152 (18KB). tgt at 67584 (2KB).
// Per-wave stage share = 4KB = 4 GLDS. Stage 2 chunks ahead; vmcnt(4) waits
// own-chunk arrival (4 instrs of next chunk stay in flight).
#define ITERTOP(BUFP) do { \
    BUFP = LDSM + (cslot << 14); \
    asm volatile("s_waitcnt vmcnt(4)" ::: "memory"); \
    __builtin_amdgcn_s_barrier(); \
    int ss_ = (cslot == 0) ? 2 : cslot - 1; \
    const char* sc_ = sp + (wv << 12) + (lane << 4); \
    char* dc_ = LDSM + (ss_ << 14) + (wv << 12); \
    GLDS(sc_, dc_); GLDS(sc_ + 1024, dc_ + 1024); \
    GLDS(sc_ + 2048, dc_ + 2048); GLDS(sc_ + 3072, dc_ + 3072); \
    sp += 16384; if (sp == send) sp = sbase; \
    cslot = (cslot == 2) ? 0 : cslot + 1; \
    __builtin_amdgcn_sched_barrier(0); \
} while (0)

static __device__ __forceinline__ void mfma_chunk(
    const char* bufp, int lane, const bf16x8 (&xpf)[2][4], f32x4 (&acc)[8])
{
    #pragma unroll
    for (int cfp = 0; cfp < 2; ++cfp)
        #pragma unroll
        for (int cl = 0; cl < 2; ++cl) {
            f32x4 a0 = {0.f, 0.f, 0.f, 0.f}, a1 = a0;
            #pragma unroll
            for (int ss = 0; ss < 4; ++ss) {
                bf16x8 a = *(const bf16x8*)(bufp + ((((cfp * 2 + cl) * 4 + ss) * 64 + lane) << 4));
                a0 = MFMA(a, xpf[0][ss], a0);
                a1 = MFMA(a, xpf[1][ss], a1);
            }
            acc[cfp * 4 + cl * 2 + 0] = a0;
            acc[cfp * 4 + cl * 2 + 1] = a1;
        }
}

template<bool LEAN>
static __device__ __forceinline__ void epi8(
    const f32x4 (&acc)[8], int ch, const float* gq, int lg4,
    const int (&tgt)[2], float (&lsum)[2], float (&bv)[2], int (&bi)[2],
    float (&pick)[2])
{
    #pragma unroll
    for (int cfp = 0; cfp < 2; ++cfp)
        #pragma unroll
        for (int cl = 0; cl < 2; ++cl) {
            int cfg = ch * 4 + cfp * 2 + cl;
            float4 gv = *(const float4*)(gq + cfg * 16 + lg4 * 4);
            int cbb = cfg * 16 + lg4 * 4;
            #pragma unroll
            for (int rf = 0; rf < 2; ++rf) {
                const f32x4& A = acc[cfp * 4 + cl * 2 + rf];
                float l0 = A[0] - gv.x, l1 = A[1] - gv.y;
                float l2 = A[2] - gv.z, l3 = A[3] - gv.w;
                lsum[rf] += (EXP2(l0) + EXP2(l1)) + (EXP2(l2) + EXP2(l3));
                if (!LEAN) {
                    float m01 = fmaxf(l0, l1), m23 = fmaxf(l2, l3);
                    float lm = fmaxf(m01, m23);
                    int jl = (m23 > m01) ? ((l3 > l2) ? 3 : 2) : ((l1 > l0) ? 1 : 0);
                    if (lm > bv[rf]) { bv[rf] = lm; bi[rf] = cbb + jl; }
                }
                if ((tgt[rf] >> 2) == (cbb >> 2)) {
                    int myj = tgt[rf] & 3;
                    pick[rf] = (myj & 2) ? ((myj & 1) ? l3 : l2) : ((myj & 1) ? l1 : l0);
                }
            }
        }
}

template<bool LEAN>
static __device__ __forceinline__ void q_body(
    int q, char* LDSM, const float* gb,
    const char*& sp, const char* sbase, const char* send, int& cslot,
    int wv, int lane, int l15, int lg4,
    bf16x8 (&xb)[2][8], const unsigned short* tab, float& loss)
{
    int tgt[2];
    {
        const int* tl = (const int*)(LDSM + 67584);
        tgt[0] = tl[(wv * 4 + q) * 32 + l15];
        tgt[1] = tl[(wv * 4 + q) * 32 + 16 + l15];
    }

    // ---- GEMM1: xp = x·Win^T + b_in (4 chunks) ----
    bf16x8 xpf[2][4];
    #pragma unroll
    for (int S = 0; S < 4; ++S) {
        const char* bufp;
        ITERTOP(bufp);
        f32x4 a00 = {0.f, 0.f, 0.f, 0.f}, a01 = a00, a10 = a00, a11 = a00;
        #pragma unroll
        for (int ss = 0; ss < 8; ++ss) {
            bf16x8 w0 = *(const bf16x8*)(bufp + (((ss) * 64 + lane) << 4));
            bf16x8 w1 = *(const bf16x8*)(bufp + (((8 + ss) * 64 + lane) << 4));
            a00 = MFMA(w0, xb[0][ss], a00);
            a01 = MFMA(w0, xb[1][ss], a01);
            a10 = MFMA(w1, xb[0][ss], a10);
            a11 = MFMA(w1, xb[1][ss], a11);
        }
        float4 b0 = *(const float4*)(gb + 4096 + q * 128 + 32 * S + 4 * lg4);
        float4 b1 = *(const float4*)(gb + 4096 + q * 128 + 32 * S + 16 + 4 * lg4);
        int4 u0, u1;
        u0.x = pk2(a00[0] + b0.x, a00[1] + b0.y);
        u0.y = pk2(a00[2] + b0.z, a00[3] + b0.w);
        u0.z = pk2(a10[0] + b1.x, a10[1] + b1.y);
        u0.w = pk2(a10[2] + b1.z, a10[3] + b1.w);
        xpf[0][S] = *(bf16x8*)&u0;
        u1.x = pk2(a01[0] + b0.x, a01[1] + b0.y);
        u1.y = pk2(a01[2] + b0.z, a01[3] + b0.w);
        u1.z = pk2(a11[0] + b1.x, a11[1] + b1.y);
        u1.w = pk2(a11[2] + b1.z, a11[3] + b1.w);
        xpf[1][S] = *(bf16x8*)&u1;
    }

    // ---- GEMM2: logits2 vs 1024 codes, A/B-pipelined epilogue ----
    const float* gq = gb + (q << 10);
    float lsum[2] = {0.f, 0.f};
    float bv[2]   = {-1e30f, -1e30f};
    int   bi[2]   = {0, 0};
    float pick[2] = {0.f, 0.f};
    f32x4 A[8], Bq[8];
    {
        const char* bufp;
        ITERTOP(bufp);
        mfma_chunk(bufp, lane, xpf, A);
    }
    #pragma unroll 1
    for (int t = 0; t < 7; ++t) {
        {
            const char* bufp;
            ITERTOP(bufp);
            mfma_chunk(bufp, lane, xpf, Bq);
            epi8<LEAN>(A, 2 * t, gq, lg4, tgt, lsum, bv, bi, pick);
        }
        {
            const char* bufp;
            ITERTOP(bufp);
            mfma_chunk(bufp, lane, xpf, A);
            epi8<LEAN>(Bq, 2 * t + 1, gq, lg4, tgt, lsum, bv, bi, pick);
        }
    }
    {
        const char* bufp;
        ITERTOP(bufp);
        mfma_chunk(bufp, lane, xpf, Bq);
        epi8<LEAN>(A, 14, gq, lg4, tgt, lsum, bv, bi, pick);
    }
    epi8<LEAN>(Bq, 15, gq, lg4, tgt, lsum, bv, bi, pick);

    // ---- combine lane-groups ----
    #pragma unroll
    for (int rf = 0; rf < 2; ++rf) {
        #pragma unroll
        for (int off = 16; off <= 32; off <<= 1) {
            lsum[rf] += __shfl_xor(lsum[rf], off);
            pick[rf] += __shfl_xor(pick[rf], off);
            if (!LEAN) {
                float om = __shfl_xor(bv[rf], off);
                int   ob = __shfl_xor(bi[rf], off);
                if (om > bv[rf] || (om == bv[rf] && ob < bi[rf])) { bv[rf] = om; bi[rf] = ob; }
            }
        }
        if (lane < 16) loss += LOG2(lsum[rf]) - pick[rf];
    }

    // ---- residual update ----
    if (!LEAN) {
        const unsigned short* tq = tab + ((size_t)q << 18);
        #pragma unroll
        for (int rf = 0; rf < 2; ++rf) {
            const unsigned short* trow = tq + ((size_t)bi[rf] << 8) + (lg4 << 3);
            #pragma unroll
            for (int s = 0; s < 8; ++s) {
                int4 tv = *(const int4*)(trow + (s << 5));
                int4 xv = *(int4*)&xb[rf][s];
                int4 ov;
                ov.x = sub2(xv.x, tv.x); ov.y = sub2(xv.y, tv.y);
                ov.z = sub2(xv.z, tv.z); ov.w = sub2(xv.w, tv.w);
                *(int4*)&xb[rf][s] = ov;
            }
        }
    }
}

__global__ __launch_bounds__(256, 2) void rvq_k(
    const float* __restrict__ X,              // (B,256,4096) f32
    const unsigned short* __restrict__ stream,
    const float* __restrict__ gbias,          // [g 4096][bias 512] f32
    const unsigned short* __restrict__ tab,   // (3,1024,256) bf16
    const int* __restrict__ tlc,
    float* __restrict__ accp)
{
    __shared__ __align__(16) char LDSM[69632]; // 48K ring + 18K gb + 2K tgt

    const int tid  = threadIdx.x;
    const int lane = tid & 63;
    const int wv   = tid >> 6;
    const int l15  = lane & 15;
    const int lg4  = lane >> 4;
    const int row_base = blockIdx.x * 128 + wv * 32;

    // residual fragments: 32 rows x 256 d, bf16, loaded+transposed in-register
    bf16x8 xb[2][8];
    #pragma unroll
    for (int rf = 0; rf < 2; ++rf) {
        const int row = row_base + rf * 16 + l15;
        const float* xpr = X + ((size_t)(row >> 12) << 20) + (row & (T_ - 1));
        #pragma unroll
        for (int s = 0; s < 8; ++s) {
            float f[8];
            #pragma unroll
            for (int j = 0; j < 8; ++j)
                f[j] = xpr[(size_t)((s << 5) + (lg4 << 3) + j) << 12];
            int4 u;
            u.x = pk2(f[0], f[1]); u.y = pk2(f[2], f[3]);
            u.z = pk2(f[4], f[5]); u.w = pk2(f[6], f[7]);
            xb[rf][s] = *(bf16x8*)&u;
        }
    }

    // tlc prologue: each lane loads q=lg4's targets for its 2 rows -> LDS
    {
        int* tl = (int*)(LDSM + 67584);
        int q0 = lg4;
        int r0 = row_base + l15, r1 = row_base + 16 + l15;
        int t0 = tlc[(size_t)(r0 >> 12) * (NQn * T_) + q0 * T_ + (r0 & (T_ - 1))];
        int t1 = tlc[(size_t)(r1 >> 12) * (NQn * T_) + q0 * T_ + (r1 & (T_ - 1))];
        tl[(wv * 4 + q0) * 32 + l15] = t0;
        tl[(wv * 4 + q0) * 32 + 16 + l15] = t1;
    }
    __builtin_amdgcn_sched_barrier(0);

    // gb staging (18KB) + first two chunks
    const char* sbase = (const char*)stream;
    const char* send  = sbase + 80 * 16384;
    {
        const char* gs = (const char*)gbias;
        #pragma unroll
        for (int k = 0; k < 4; ++k)
            GLDS(gs + (((k * 4 + wv) * 64 + lane) << 4),
                 LDSM + 49152 + ((k * 4 + wv) << 10));
        if (wv < 2)
            GLDS(gs + 16384 + ((wv * 64 + lane) << 4),
                 LDSM + 49152 + 16384 + (wv << 10));
    }
    {
        const char* s0 = sbase + (wv << 12) + (lane << 4);
        char* d0 = LDSM + (wv << 12);
        GLDS(s0, d0); GLDS(s0 + 1024, d0 + 1024);
        GLDS(s0 + 2048, d0 + 2048); GLDS(s0 + 3072, d0 + 3072);
        const char* s1 = s0 + 16384;
        char* d1 = d0 + 16384;
        GLDS(s1, d1); GLDS(s1 + 1024, d1 + 1024);
        GLDS(s1 + 2048, d1 + 2048); GLDS(s1 + 3072, d1 + 3072);
    }
    const char* sp = sbase + 32768;
    int cslot = 0;
    __syncthreads();   // tgt LDS visible; staging counts consistent

    float loss = 0.f;
    const float* gb = (const float*)(LDSM + 49152);

    #pragma unroll 1
    for (int q = 0; q < 3; ++q)
        q_body<false>(q, LDSM, gb, sp, sbase, send, cslot,
                      wv, lane, l15, lg4, xb, tab, loss);
    q_body<true>(3, LDSM, gb, sp, sbase, send, cslot,
                 wv, lane, l15, lg4, xb, tab, loss);

    asm volatile("s_waitcnt vmcnt(0)" ::: "memory");  // drain dummy tail stages
    #pragma unroll
    for (int off = 1; off < 64; off <<= 1) loss += __shfl_xor(loss, off);
    if (lane == 0) atomicAdd(accp, loss * 0.69314718056f);
}

// ---------------------------------------------------------------- launch
extern "C" void kernel_launch(void* const* d_in, const int* in_sizes, int n_in,
                              void* d_out, int out_size, void* d_ws, size_t ws_size,
                              hipStream_t stream_)
{
    (void)in_sizes; (void)n_in; (void)out_size; (void)ws_size;
    const float* dstart = (const float*)d_in[0];
    const int*   tlc    = (const int*)d_in[1];
    const float* Win    = (const float*)d_in[2];
    const float* bin    = (const float*)d_in[3];
    const float* Wout   = (const float*)d_in[4];
    const float* bout   = (const float*)d_in[5];
    const float* emb    = (const float*)d_in[6];

    char* ws = (char*)d_ws;
    size_t off = 0;
    unsigned short* strm = (unsigned short*)(ws + off); off += (size_t)80 * 16384;       // 1.25 MB
    unsigned short* tab  = (unsigned short*)(ws + off); off += (size_t)3 * K_ * D_ * 2;  // 1.5 MB
    float*          gbias= (float*)(ws + off);          off += (size_t)4608 * 4;         // 18 KB
    float*          accp = (float*)(ws + off);          off += 256;

    zero_acc_k<<<1, 1, 0, stream_>>>(accp);
    reformat_k<<<321, 256, 0, stream_>>>(Win, bin, emb, strm, gbias);
    prep_tab_k<<<256, 256, 0, stream_>>>(Wout, bout, emb, tab, gbias);
    rvq_k<<<512, 256, 0, stream_>>>(dstart, strm, gbias, tab, tlc, accp);
    final_k<<<1, 1, 0, stream_>>>(accp, (float*)d_out);
}

// Round 9
// 159.569 us; speedup vs baseline: 3.4318x; 1.0580x over previous
//
#include <hip/hip_runtime.h>
#include <math.h>

#define B_   16
#define D_   256
#define T_   4096
#define NQn  8
#define K_   1024
#define DC_  128
#define M_   65536

typedef short bf16x8 __attribute__((ext_vector_type(8)));
typedef float f32x4  __attribute__((ext_vector_type(4)));

static __device__ __forceinline__ unsigned short f2bf(float f) {
    unsigned u = __float_as_uint(f);
    unsigned r = (u + 0x7fffu + ((u >> 16) & 1u)) >> 16;
    return (unsigned short)r;
}

// packed f32x2 -> bf16x2 (RNE), 1 instruction
static __device__ __forceinline__ int pk2(float lo, float hi) {
    int r;
    asm("v_cvt_pk_bf16_f32 %0, %1, %2" : "=v"(r) : "v"(lo), "v"(hi));
    return r;
}
// (x - t) elementwise on packed bf16x2
static __device__ __forceinline__ int sub2(int x, int t) {
    float xl = __uint_as_float(((unsigned)x) << 16);
    float xh = __uint_as_float(((unsigned)x) & 0xFFFF0000u);
    float tl = __uint_as_float(((unsigned)t) << 16);
    float th = __uint_as_float(((unsigned)t) & 0xFFFF0000u);
    return pk2(xl - tl, xh - th);
}

static __device__ __forceinline__ f32x4 MFMA(bf16x8 a, bf16x8 b, f32x4 c) {
    return __builtin_amdgcn_mfma_f32_16x16x32_bf16(a, b, c, 0, 0, 0);
}

#define EXP2(x) __builtin_amdgcn_exp2f(x)
#define LOG2(x) __builtin_amdgcn_logf(x)

__global__ void zero_acc_k(float* acc) { acc[0] = 0.f; }
__global__ void final_k(const float* __restrict__ acc, float* __restrict__ out) {
    out[0] = acc[0] * (1.f / 262144.f);   // / (4 * B * T)
}

// ---------------------------------------------------------------- stream reformat
// Per-q 320KB: [Win_perm 4 chunks][emb_perm 16 chunks], chunk=16KB, wave read-order.
// emb scaled by 1/(64*ln2) for exp2-domain logits.
__global__ __launch_bounds__(256) void reformat_k(
    const float* __restrict__ Win, const float* __restrict__ bin,
    const float* __restrict__ emb, unsigned short* __restrict__ stream,
    float* __restrict__ gbias)
{
    const int bid = blockIdx.x;
    const int tid = threadIdx.x;
    if (bid == 320) {
        gbias[4096 + tid]       = bin[tid];
        gbias[4096 + 256 + tid] = bin[256 + tid];
        return;
    }
    int u = bid * 256 + tid;              // 16B unit, 0..81919
    int idx = u >> 10;                    // chunk 0..79
    int q = idx / 20, r = idx - q * 20;
    int w = u & 1023;
    int lane = w & 63, blk = w >> 6;
    int l15 = lane & 15, lg4 = lane >> 4;
    unsigned short o[8];
    if (r < 4) {
        int c  = 32 * r + 16 * (blk >> 3) + l15;
        int d0 = 32 * (blk & 7) + 8 * lg4;
        const float* s = Win + ((size_t)q * DC_ + c) * D_ + d0;
        #pragma unroll
        for (int j = 0; j < 8; ++j) o[j] = f2bf(s[j]);
    } else {
        int ch = r - 4;
        int code = (ch * 4 + (blk >> 2)) * 16 + l15;
        int s4 = blk & 3;
        const float* s = emb + ((size_t)q * K_ + code) * DC_ + 32 * s4 + 4 * lg4;
        const float ESC = 1.44269504089f / 64.0f;
        #pragma unroll
        for (int j = 0; j < 8; ++j)
            o[j] = f2bf(s[16 * (j >> 2) + (j & 3)] * ESC);
    }
    *(int4*)&stream[(size_t)u * 8] = *(int4*)o;
}

// ---------------------------------------------------------------- tab + g
// g[k] = |e_k|^2/(128*ln2) ; tab[k][d] = embed[k]·Wout[d] + b_out[d]
__global__ __launch_bounds__(256) void prep_tab_k(
    const float* __restrict__ Wout, const float* __restrict__ bout,
    const float* __restrict__ emb,
    unsigned short* __restrict__ tab, float* __restrict__ gbias)
{
    __shared__ float E[16][128];
    const int iq = blockIdx.x >> 6;
    const int k0 = (blockIdx.x & 63) << 4;
    const int tid = threadIdx.x;
    {
        const float* src = emb + ((size_t)iq * K_ + k0) * DC_;
        #pragma unroll
        for (int it = 0; it < 2; ++it) {
            int lin = it * 1024 + tid * 4;
            float4 v = *(const float4*)(src + lin);
            *(float4*)&E[lin >> 7][lin & 127] = v;
        }
    }
    __syncthreads();
    if (tid < 16) {
        float e2 = 0.f;
        for (int c2 = 0; c2 < 128; ++c2) { float e = E[tid][c2]; e2 += e * e; }
        gbias[iq * K_ + k0 + tid] = e2 * (1.44269504089f / 128.f);
    }
    if (iq < 3) {
        const int d = tid;
        float acc[16];
        #pragma unroll
        for (int kk = 0; kk < 16; ++kk) acc[kk] = 0.f;
        const float* wp = Wout + ((size_t)iq * D_ + d) * DC_;
        for (int c2 = 0; c2 < 128; ++c2) {
            float w = wp[c2];
            #pragma unroll
            for (int kk = 0; kk < 16; ++kk) acc[kk] = fmaf(E[kk][c2], w, acc[kk]);
        }
        float bo = bout[iq * D_ + d];
        unsigned short* tq = tab + ((size_t)iq << 18);
        #pragma unroll
        for (int kk = 0; kk < 16; ++kk)
            tq[((size_t)(k0 + kk) << 8) + d] = f2bf(acc[kk] + bo);
    }
}

// ---------------------------------------------------------------- fused RVQ
#define GLDS(SRC, DST) __builtin_amdgcn_global_load_lds( \
    (const __attribute__((address_space(1))) unsigned int*)(SRC), \
    (__attribute__((address_space(3))) unsigned int*)(DST), 16, 0, 0)

// ring: 3 x 16KB slots at LDSM+0..48K. gb at 49152 (18KB). tgt at 67584 (2KB).
#define ITERTOP(BUFP) do { \
    BUFP = LDSM + (cslot << 14); \
    asm volatile("s_waitcnt vmcnt(4)" ::: "memory"); \
    __builtin_amdgcn_s_barrier(); \
    int ss_ = (cslot == 0) ? 2 : cslot - 1; \
    const char* sc_ = sp + (wv << 12) + (lane << 4); \
    char* dc_ = LDSM + (ss_ << 14) + (wv << 12); \
    GLDS(sc_, dc_); GLDS(sc_ + 1024, dc_ + 1024); \
    GLDS(sc_ + 2048, dc_ + 2048); GLDS(sc_ + 3072, dc_ + 3072); \
    sp += 16384; if (sp == send) sp = sbase; \
    cslot = (cslot == 2) ? 0 : cslot + 1; \
    __builtin_amdgcn_sched_barrier(0); \
} while (0)

static __device__ __forceinline__ void mfma_chunk(
    const char* bufp, int lane, const bf16x8 (&xpf)[2][4], f32x4 (&acc)[8])
{
    #pragma unroll
    for (int cfp = 0; cfp < 2; ++cfp)
        #pragma unroll
        for (int cl = 0; cl < 2; ++cl) {
            f32x4 a0 = {0.f, 0.f, 0.f, 0.f}, a1 = a0;
            #pragma unroll
            for (int ss = 0; ss < 4; ++ss) {
                bf16x8 a = *(const bf16x8*)(bufp + ((((cfp * 2 + cl) * 4 + ss) * 64 + lane) << 4));
                a0 = MFMA(a, xpf[0][ss], a0);
                a1 = MFMA(a, xpf[1][ss], a1);
            }
            acc[cfp * 4 + cl * 2 + 0] = a0;
            acc[cfp * 4 + cl * 2 + 1] = a1;
        }
}

// EPI: exp2 + packed-index argmax. Packed layout low 8 bits: [7:6]=i, [5:0]=cfg.
template<bool LEAN>
static __device__ __forceinline__ void epi8(
    const f32x4 (&acc)[8], int ch, const float* gq, int lg4,
    float (&lsum)[2], float (&bv)[2])
{
    #pragma unroll
    for (int cfp = 0; cfp < 2; ++cfp)
        #pragma unroll
        for (int cl = 0; cl < 2; ++cl) {
            int cfg = ch * 4 + cfp * 2 + cl;
            float4 gv = *(const float4*)(gq + cfg * 16 + lg4 * 4);
            #pragma unroll
            for (int rf = 0; rf < 2; ++rf) {
                const f32x4& A = acc[cfp * 4 + cl * 2 + rf];
                float e0 = EXP2(A[0] - gv.x);
                float e1 = EXP2(A[1] - gv.y);
                float e2 = EXP2(A[2] - gv.z);
                float e3 = EXP2(A[3] - gv.w);
                if (LEAN) {
                    lsum[rf] += (e0 + e1) + (e2 + e3);
                } else {
                    unsigned cv = (unsigned)cfg;
                    float p0 = __uint_as_float((__float_as_uint(e0) & 0xFFFFFF00u) | cv);
                    float p1 = __uint_as_float(((__float_as_uint(e1) & 0xFFFFFF00u) | cv) | 64u);
                    float p2 = __uint_as_float(((__float_as_uint(e2) & 0xFFFFFF00u) | cv) | 128u);
                    float p3 = __uint_as_float(((__float_as_uint(e3) & 0xFFFFFF00u) | cv) | 192u);
                    lsum[rf] += (p0 + p1) + (p2 + p3);
                    bv[rf] = fmaxf(bv[rf], fmaxf(fmaxf(p0, p1), fmaxf(p2, p3)));
                }
            }
        }
}

template<bool LEAN>
static __device__ __forceinline__ void q_body(
    int q, char* LDSM, const float* gb,
    const char*& sp, const char* sbase, const char* send, int& cslot,
    int wv, int lane, int l15, int lg4,
    bf16x8 (&xb)[2][8], const unsigned short* tab, const char* sq, float& loss)
{
    int tgt[2];
    {
        const int* tl = (const int*)(LDSM + 67584);
        tgt[0] = tl[(wv * 4 + q) * 32 + l15];
        tgt[1] = tl[(wv * 4 + q) * 32 + 16 + l15];
    }

    // ---- GEMM1: xp = x·Win^T + b_in (4 chunks) ----
    bf16x8 xpf[2][4];
    #pragma unroll
    for (int S = 0; S < 4; ++S) {
        const char* bufp;
        ITERTOP(bufp);
        f32x4 a00 = {0.f, 0.f, 0.f, 0.f}, a01 = a00, a10 = a00, a11 = a00;
        #pragma unroll
        for (int ss = 0; ss < 8; ++ss) {
            bf16x8 w0 = *(const bf16x8*)(bufp + (((ss) * 64 + lane) << 4));
            bf16x8 w1 = *(const bf16x8*)(bufp + (((8 + ss) * 64 + lane) << 4));
            a00 = MFMA(w0, xb[0][ss], a00);
            a01 = MFMA(w0, xb[1][ss], a01);
            a10 = MFMA(w1, xb[0][ss], a10);
            a11 = MFMA(w1, xb[1][ss], a11);
        }
        float4 b0 = *(const float4*)(gb + 4096 + q * 128 + 32 * S + 4 * lg4);
        float4 b1 = *(const float4*)(gb + 4096 + q * 128 + 32 * S + 16 + 4 * lg4);
        int4 u0, u1;
        u0.x = pk2(a00[0] + b0.x, a00[1] + b0.y);
        u0.y = pk2(a00[2] + b0.z, a00[3] + b0.w);
        u0.z = pk2(a10[0] + b1.x, a10[1] + b1.y);
        u0.w = pk2(a10[2] + b1.z, a10[3] + b1.w);
        xpf[0][S] = *(bf16x8*)&u0;
        u1.x = pk2(a01[0] + b0.x, a01[1] + b0.y);
        u1.y = pk2(a01[2] + b0.z, a01[3] + b0.w);
        u1.z = pk2(a11[0] + b1.x, a11[1] + b1.y);
        u1.w = pk2(a11[2] + b1.z, a11[3] + b1.w);
        xpf[1][S] = *(bf16x8*)&u1;
    }

    // ---- GEMM2: logits2 vs 1024 codes, A/B-pipelined epilogue ----
    const float* gq = gb + (q << 10);
    float lsum[2] = {0.f, 0.f};
    float bv[2]   = {0.f, 0.f};
    int   bi[2]   = {0, 0};
    f32x4 A[8], Bq[8];
    {
        const char* bufp;
        ITERTOP(bufp);
        mfma_chunk(bufp, lane, xpf, A);
    }
    #pragma unroll 1
    for (int t = 0; t < 7; ++t) {
        {
            const char* bufp;
            ITERTOP(bufp);
            mfma_chunk(bufp, lane, xpf, Bq);
            epi8<LEAN>(A, 2 * t, gq, lg4, lsum, bv);
        }
        {
            const char* bufp;
            ITERTOP(bufp);
            mfma_chunk(bufp, lane, xpf, A);
            epi8<LEAN>(Bq, 2 * t + 1, gq, lg4, lsum, bv);
        }
    }
    {
        const char* bufp;
        ITERTOP(bufp);
        mfma_chunk(bufp, lane, xpf, Bq);
        epi8<LEAN>(A, 14, gq, lg4, lsum, bv);
    }
    epi8<LEAN>(Bq, 15, gq, lg4, lsum, bv);

    // ---- pick = dot(xp_row, F[tgt_row]) - g[tgt] via MFMA diagonal ----
    float pickv[2];
    #pragma unroll
    for (int rf = 0; rf < 2; ++rf) {
        int t = tgt[rf];
        const char* fb = sq + ((4 + (t >> 6)) << 14)
                       + (((((t >> 4) & 3) << 8) + (lg4 << 4) + (t & 15)) << 4);
        bf16x8 f0 = *(const bf16x8*)(fb);
        bf16x8 f1 = *(const bf16x8*)(fb + 1024);
        bf16x8 f2 = *(const bf16x8*)(fb + 2048);
        bf16x8 f3 = *(const bf16x8*)(fb + 3072);
        f32x4 pa = {0.f, 0.f, 0.f, 0.f};
        pa = MFMA(f0, xpf[rf][0], pa);
        pa = MFMA(f1, xpf[rf][1], pa);
        pa = MFMA(f2, xpf[rf][2], pa);
        pa = MFMA(f3, xpf[rf][3], pa);
        int r = l15 & 3;
        float dv = (r == 0) ? pa[0] : ((r == 1) ? pa[1] : ((r == 2) ? pa[2] : pa[3]));
        float gt = gq[t];
        pickv[rf] = (lg4 == (l15 >> 2)) ? (dv - gt) : 0.f;
    }

    // ---- combine lane-groups ----
    #pragma unroll
    for (int rf = 0; rf < 2; ++rf) {
        float pk10 = 0.f;
        if (!LEAN) {
            unsigned pb = __float_as_uint(bv[rf]);
            unsigned code = ((pb & 63u) << 4) | (unsigned)(lg4 << 2) | ((pb >> 6) & 3u);
            pk10 = __uint_as_float((pb & 0xFFFFFC00u) | code);
        }
        #pragma unroll
        for (int off = 16; off <= 32; off <<= 1) {
            lsum[rf]  += __shfl_xor(lsum[rf], off);
            pickv[rf] += __shfl_xor(pickv[rf], off);
            if (!LEAN) pk10 = fmaxf(pk10, __shfl_xor(pk10, off));
        }
        if (!LEAN) bi[rf] = (int)(__float_as_uint(pk10) & 1023u);
        if (lane < 16) loss += LOG2(lsum[rf]) - pickv[rf];
    }

    // ---- residual update ----
    if (!LEAN) {
        const unsigned short* tq = tab + ((size_t)q << 18);
        #pragma unroll
        for (int rf = 0; rf < 2; ++rf) {
            const unsigned short* trow = tq + ((size_t)bi[rf] << 8) + (lg4 << 3);
            #pragma unroll
            for (int s = 0; s < 8; ++s) {
                int4 tv = *(const int4*)(trow + (s << 5));
                int4 xv = *(int4*)&xb[rf][s];
                int4 ov;
                ov.x = sub2(xv.x, tv.x); ov.y = sub2(xv.y, tv.y);
                ov.z = sub2(xv.z, tv.z); ov.w = sub2(xv.w, tv.w);
                *(int4*)&xb[rf][s] = ov;
            }
        }
    }
}

__global__ __launch_bounds__(256, 2) void rvq_k(
    const float* __restrict__ X,              // (B,256,4096) f32
    const unsigned short* __restrict__ stream,
    const float* __restrict__ gbias,          // [g 4096][bias 512] f32
    const unsigned short* __restrict__ tab,   // (3,1024,256) bf16
    const int* __restrict__ tlc,
    float* __restrict__ accp)
{
    __shared__ __align__(16) char LDSM[69632]; // 48K ring + 18K gb + 2K tgt

    const int tid  = threadIdx.x;
    const int lane = tid & 63;
    const int wv   = tid >> 6;
    const int l15  = lane & 15;
    const int lg4  = lane >> 4;
    const int row_base = blockIdx.x * 128 + wv * 32;

    // residual fragments: 32 rows x 256 d, bf16, loaded+transposed in-register
    bf16x8 xb[2][8];
    #pragma unroll
    for (int rf = 0; rf < 2; ++rf) {
        const int row = row_base + rf * 16 + l15;
        const float* xpr = X + ((size_t)(row >> 12) << 20) + (row & (T_ - 1));
        #pragma unroll
        for (int s = 0; s < 8; ++s) {
            float f[8];
            #pragma unroll
            for (int j = 0; j < 8; ++j)
                f[j] = xpr[(size_t)((s << 5) + (lg4 << 3) + j) << 12];
            int4 u;
            u.x = pk2(f[0], f[1]); u.y = pk2(f[2], f[3]);
            u.z = pk2(f[4], f[5]); u.w = pk2(f[6], f[7]);
            xb[rf][s] = *(bf16x8*)&u;
        }
    }

    // tlc prologue: each lane loads q=lg4's targets for its 2 rows -> LDS
    {
        int* tl = (int*)(LDSM + 67584);
        int q0 = lg4;
        int r0 = row_base + l15, r1 = row_base + 16 + l15;
        int t0 = tlc[(size_t)(r0 >> 12) * (NQn * T_) + q0 * T_ + (r0 & (T_ - 1))];
        int t1 = tlc[(size_t)(r1 >> 12) * (NQn * T_) + q0 * T_ + (r1 & (T_ - 1))];
        tl[(wv * 4 + q0) * 32 + l15] = t0;
        tl[(wv * 4 + q0) * 32 + 16 + l15] = t1;
    }
    __builtin_amdgcn_sched_barrier(0);

    // gb staging (18KB) + first two chunks
    const char* sbase = (const char*)stream;
    const char* send  = sbase + 80 * 16384;
    {
        const char* gs = (const char*)gbias;
        #pragma unroll
        for (int k = 0; k < 4; ++k)
            GLDS(gs + (((k * 4 + wv) * 64 + lane) << 4),
                 LDSM + 49152 + ((k * 4 + wv) << 10));
        if (wv < 2)
            GLDS(gs + 16384 + ((wv * 64 + lane) << 4),
                 LDSM + 49152 + 16384 + (wv << 10));
    }
    {
        const char* s0 = sbase + (wv << 12) + (lane << 4);
        char* d0 = LDSM + (wv << 12);
        GLDS(s0, d0); GLDS(s0 + 1024, d0 + 1024);
        GLDS(s0 + 2048, d0 + 2048); GLDS(s0 + 3072, d0 + 3072);
        const char* s1 = s0 + 16384;
        char* d1 = d0 + 16384;
        GLDS(s1, d1); GLDS(s1 + 1024, d1 + 1024);
        GLDS(s1 + 2048, d1 + 2048); GLDS(s1 + 3072, d1 + 3072);
    }
    const char* sp = sbase + 32768;
    int cslot = 0;
    __syncthreads();   // tgt LDS visible; staging counts consistent

    float loss = 0.f;
    const float* gb = (const float*)(LDSM + 49152);

    #pragma unroll 1
    for (int q = 0; q < 3; ++q)
        q_body<false>(q, LDSM, gb, sp, sbase, send, cslot,
                      wv, lane, l15, lg4, xb, tab,
                      sbase + (size_t)q * 327680, loss);
    q_body<true>(3, LDSM, gb, sp, sbase, send, cslot,
                 wv, lane, l15, lg4, xb, tab,
                 sbase + (size_t)3 * 327680, loss);

    asm volatile("s_waitcnt vmcnt(0)" ::: "memory");  // drain dummy tail stages
    #pragma unroll
    for (int off = 1; off < 64; off <<= 1) loss += __shfl_xor(loss, off);
    if (lane == 0) atomicAdd(accp, loss * 0.69314718056f);
}

// ---------------------------------------------------------------- launch
extern "C" void kernel_launch(void* const* d_in, const int* in_sizes, int n_in,
                              void* d_out, int out_size, void* d_ws, size_t ws_size,
                              hipStream_t stream_)
{
    (void)in_sizes; (void)n_in; (void)out_size; (void)ws_size;
    const float* dstart = (const float*)d_in[0];
    const int*   tlc    = (const int*)d_in[1];
    const float* Win    = (const float*)d_in[2];
    const float* bin    = (const float*)d_in[3];
    const float* Wout   = (const float*)d_in[4];
    const float* bout   = (const float*)d_in[5];
    const float* emb    = (const float*)d_in[6];

    char* ws = (char*)d_ws;
    size_t off = 0;
    unsigned short* strm = (unsigned short*)(ws + off); off += (size_t)80 * 16384;       // 1.25 MB
    unsigned short* tab  = (unsigned short*)(ws + off); off += (size_t)3 * K_ * D_ * 2;  // 1.5 MB
    float*          gbias= (float*)(ws + off);          off += (size_t)4608 * 4;         // 18 KB
    float*          accp = (float*)(ws + off);          off += 256;

    zero_acc_k<<<1, 1, 0, stream_>>>(accp);
    reformat_k<<<321, 256, 0, stream_>>>(Win, bin, emb, strm, gbias);
    prep_tab_k<<<256, 256, 0, stream_>>>(Wout, bout, emb, tab, gbias);
    rvq_k<<<512, 256, 0, stream_>>>(dstart, strm, gbias, tab, tlc, accp);
    final_k<<<1, 1, 0, stream_>>>(accp, (float*)d_out);
}